// Round 10
// baseline (4746.136 us; speedup 1.0000x reference)
//
#include <hip/hip_runtime.h>
#include <cmath>

#define S_LEN 32
#define E_DIM 128
#define H_DIM 256
#define V_DIM 512
#define NTILE 36            // BK=64: pass1 18 (a1 x w1w2w3), pass2 12, pass3 6
#define TILE_SHORTS 8192    // 16 frags x 64 lanes x 8 shorts = 16 KB
#define A_SHORTS 24576      // 12 ksub x 4 rowblk x 64 lanes x 8 = 48 KB
#define SM_BYTES 81920

typedef __attribute__((ext_vector_type(8))) short bf16x8v;
typedef __attribute__((ext_vector_type(4))) float f32x4v;

__device__ __forceinline__ float sigf(float x) { return 1.0f / (1.0f + expf(-x)); }

__device__ __forceinline__ unsigned short f2bf(float x) {      // RNE
  unsigned int b = __float_as_uint(x);
  b += 0x7FFFu + ((b >> 16) & 1u);
  return (unsigned short)(b >> 16);
}
__device__ __forceinline__ float bf2f(unsigned short u) {
  return __uint_as_float(((unsigned int)u) << 16);
}

template<int L>
__device__ __forceinline__ unsigned short lvl_bf(float x) {
  unsigned short b1 = f2bf(x);
  if (L == 1) return b1;
  float r1 = x - bf2f(b1);
  unsigned short b2 = f2bf(r1);
  if (L == 2) return b2;
  return f2bf(r1 - bf2f(b2));
}

__device__ __forceinline__ void gll16(const unsigned short* g, unsigned short* l) {
  __builtin_amdgcn_global_load_lds(
      (const __attribute__((address_space(1))) unsigned int*)g,
      (__attribute__((address_space(3))) unsigned int*)l, 16, 0, 0);
}

// ---- group flag sync (8 blocks per mb-group), device-scope, monotone -------
__device__ __forceinline__ void group_wait(int* flag, int target) {
  if (threadIdx.x == 0) {
    while (__hip_atomic_load(flag, __ATOMIC_ACQUIRE, __HIP_MEMORY_SCOPE_AGENT) < target)
      __builtin_amdgcn_s_sleep(2);
  }
  __syncthreads();
}
__device__ __forceinline__ void group_arrive(int* flag) {
  __syncthreads();
  if (threadIdx.x == 0)
    __hip_atomic_fetch_add(flag, 1, __ATOMIC_RELEASE, __HIP_MEMORY_SCOPE_AGENT);
}

// ---------------------------------------------------------------------------
// prep: W fragment stream (BK=64 tiles) — EXACT round-9 layout; init block
// zeroes tok + flags with agent-scope stores.
// ---------------------------------------------------------------------------
__global__ void prep_weights(const float* __restrict__ eWih, const float* __restrict__ eWhh,
                             const float* __restrict__ dWih, const float* __restrict__ dWhh,
                             unsigned short* __restrict__ We, unsigned short* __restrict__ Wd,
                             int* __restrict__ tok, int* __restrict__ flags)
{
  const int b = blockIdx.x;
  if (b >= 576) {                        // init block
    for (int i = threadIdx.x; i < 2048; i += 256)
      __hip_atomic_store(&tok[i], 0, __ATOMIC_RELAXED, __HIP_MEMORY_SCOPE_AGENT);
    if (threadIdx.x < 32)
      __hip_atomic_store(&flags[threadIdx.x], 0, __ATOMIC_RELAXED, __HIP_MEMORY_SCOPE_AGENT);
    return;
  }
  const int j    = b % NTILE;
  const int rest = b / NTILE;
  const int nb   = rest & 7;
  const int set  = rest >> 3;
  const float* Wih = set ? dWih : eWih;
  const float* Whh = set ? dWhh : eWhh;
  unsigned short* dst = (set ? Wd : We) + ((size_t)nb * NTILE + j) * TILE_SHORTS;
  const int jj = (j < 18) ? j : (j < 30 ? j - 18 : j - 30);

  for (int cpos = threadIdx.x; cpos < 1024; cpos += 256) {
    int fi = cpos >> 6, l = cpos & 63;
    int kh = fi >> 3, wc = (fi >> 2) & 1, g = fi & 3;
    int n   = g * H_DIM + nb * 32 + wc * 16 + (l & 15);
    int sk0 = jj * 64 + kh * 32 + (l >> 4) * 8;
    int lvl = sk0 / 384;
    int kk  = sk0 - lvl * 384;
    unsigned short o8[8];
    #pragma unroll
    for (int e = 0; e < 8; ++e) {
      int k = kk + e;
      float v = (k < E_DIM) ? Wih[(size_t)n * E_DIM + k]
                            : Whh[(size_t)n * H_DIM + (k - E_DIM)];
      unsigned short b1 = f2bf(v);
      float r1 = v - bf2f(b1);
      unsigned short b2 = f2bf(r1);
      unsigned short b3 = f2bf(r1 - bf2f(b2));
      o8[e] = (lvl == 0) ? b1 : (lvl == 1) ? b2 : b3;
    }
    uint4 pk;
    pk.x = (unsigned)o8[0] | ((unsigned)o8[1] << 16);
    pk.y = (unsigned)o8[2] | ((unsigned)o8[3] << 16);
    pk.z = (unsigned)o8[4] | ((unsigned)o8[5] << 16);
    pk.w = (unsigned)o8[6] | ((unsigned)o8[7] << 16);
    *(uint4*)&dst[(size_t)cpos * 8] = pk;
  }
}

// stage level-L bf16 of A=[emb[token] | h(regs)] into fragment layout — round-9 math
template<int L>
__device__ __forceinline__ void stage_A_mega(unsigned short* Ax,
                                             const float* __restrict__ esrc,
                                             const float4* hv,
                                             int arow, int q4) {
  const int rowblk = arow >> 4;
  const int rlo    = arow & 15;
  #pragma unroll
  for (int j = 0; j < 8; ++j) {
    int k0 = q4 * 4 + 16 * j;
    float4 v = *(const float4*)(esrc + k0);
    unsigned short s0 = lvl_bf<L>(v.x), s1 = lvl_bf<L>(v.y),
                   s2 = lvl_bf<L>(v.z), s3 = lvl_bf<L>(v.w);
    uint2 p; p.x = (unsigned)s0 | ((unsigned)s1 << 16);
             p.y = (unsigned)s2 | ((unsigned)s3 << 16);
    int lane_w = rlo + ((k0 & 31) >> 3) * 16;
    *(uint2*)&Ax[(((k0 >> 5) * 4 + rowblk) * 64 + lane_w) * 8 + (k0 & 7)] = p;
  }
  #pragma unroll
  for (int j = 0; j < 16; ++j) {
    int k0 = q4 * 4 + 16 * j;
    int kA = E_DIM + k0;
    float4 v = hv[j];
    unsigned short s0 = lvl_bf<L>(v.x), s1 = lvl_bf<L>(v.y),
                   s2 = lvl_bf<L>(v.z), s3 = lvl_bf<L>(v.w);
    uint2 p; p.x = (unsigned)s0 | ((unsigned)s1 << 16);
             p.y = (unsigned)s2 | ((unsigned)s3 << 16);
    int lane_w = rlo + ((kA & 31) >> 3) * 16;
    *(uint2*)&Ax[(((kA >> 5) * 4 + rowblk) * 64 + lane_w) * 8 + (kA & 7)] = p;
  }
}

// ---------------------------------------------------------------------------
// Megakernel: all 32+T steps in ONE launch. 256 blocks x 256 thr (1/CU).
// Block (mb = bid>>3, nb = bid&7): lstm tile rows mb*64..+63, cols nb*32..+31
// (x4 gates); decoder declog: rows mb*64+nb*8..+7, all 512 vocab.
// h/tok cross blocks via L3 agent atomics; c lives in registers; group-of-8
// flag barrier per epoch (32 enc + 96 dec epochs).
// ---------------------------------------------------------------------------
__launch_bounds__(256)
__global__ void seq2seq_mega(
    const int* __restrict__ source,
    const float* __restrict__ enc_emb, const float* __restrict__ enc_bih, const float* __restrict__ enc_bhh,
    const float* __restrict__ dec_emb, const float* __restrict__ dec_bih, const float* __restrict__ dec_bhh,
    const unsigned short* __restrict__ We, const unsigned short* __restrict__ Wd,
    const float* __restrict__ fcW, const float* __restrict__ fcb,
    float* __restrict__ out, float* __restrict__ hA, float* __restrict__ hB,
    int* __restrict__ tok, int* __restrict__ flags, int T)
{
  __shared__ __align__(16) unsigned char smem[SM_BYTES];
  unsigned short* Ax  = (unsigned short*)smem;                    // 49152 B
  unsigned short* Bt0 = (unsigned short*)(smem + 49152);          // 16384 B
  unsigned short* Bt1 = (unsigned short*)(smem + 65536);          // 16384 B
  float (*dAs)[264]      = (float (*)[264])smem;                  // 8448 B
  float (*dBs)[16][V_DIM] = (float (*)[16][V_DIM])(smem + 8448);  // 65536 B

  const int tid  = threadIdx.x;
  const int lane = tid & 63;
  const int w    = tid >> 6;
  const int bid  = blockIdx.x;
  const int mb   = bid >> 3;
  const int nb   = bid & 7;
  const int m0   = mb * 64;
  int* flag = &flags[mb];
  int E = 0;

  const int arow = tid >> 2;
  const int q4   = tid & 3;
  const int wm = (tid >> 6) & 1;
  const int wc = tid >> 7;
  const int lr = tid & 15;
  const int l4 = lane >> 4;
  const int col = nb * 32 + wc * 16 + lr;

  float ebs[4], dbs[4];
  #pragma unroll
  for (int g = 0; g < 4; ++g) {
    ebs[g] = enc_bih[g * H_DIM + col] + enc_bhh[g * H_DIM + col];
    dbs[g] = dec_bih[g * H_DIM + col] + dec_bhh[g * H_DIM + col];
  }

  float c_reg[2][4] = {};
  float4 hv[16];
  #pragma unroll
  for (int j = 0; j < 16; ++j) hv[j] = make_float4(0.f, 0.f, 0.f, 0.f);

  const int nsteps = S_LEN + T;
  for (int g = 0; g < nsteps; ++g) {
    const bool enc = (g < S_LEN);

    // ================= LSTM epoch =================
    group_wait(flag, 8 * E);

    int token;
    if (enc)              token = source[(size_t)(m0 + arow) * S_LEN + g];
    else if (g == S_LEN)  token = 0;    // <SOS>
    else                  token = __hip_atomic_load(&tok[m0 + arow], __ATOMIC_RELAXED,
                                                    __HIP_MEMORY_SCOPE_AGENT);
    const float* esrc = (enc ? enc_emb : dec_emb) + (size_t)token * E_DIM;

    if (g > 0) {                        // load h_{g-1} (exact f32 bits) into regs
      const float* hprev = ((g - 1) & 1) ? hB : hA;
      const unsigned long long* hp64 =
          (const unsigned long long*)(hprev + (size_t)(m0 + arow) * H_DIM + q4 * 4);
      #pragma unroll
      for (int j = 0; j < 16; ++j) {
        unsigned long long u0 = __hip_atomic_load(hp64 + j * 8,     __ATOMIC_RELAXED, __HIP_MEMORY_SCOPE_AGENT);
        unsigned long long u1 = __hip_atomic_load(hp64 + j * 8 + 1, __ATOMIC_RELAXED, __HIP_MEMORY_SCOPE_AGENT);
        hv[j].x = __uint_as_float((unsigned)u0);
        hv[j].y = __uint_as_float((unsigned)(u0 >> 32));
        hv[j].z = __uint_as_float((unsigned)u1);
        hv[j].w = __uint_as_float((unsigned)(u1 >> 32));
      }
    }

    const unsigned short* wstream = (enc ? We : Wd) + (size_t)nb * (NTILE * TILE_SHORTS);
    auto stage_B = [&](int j, unsigned short* dstb) {
      const unsigned short* src = wstream + (size_t)j * TILE_SHORTS + w * 2048 + lane * 8;
      unsigned short* dstp = dstb + w * 2048;
      #pragma unroll
      for (int i = 0; i < 4; ++i) gll16(src + i * 512, dstp + i * 512);
    };

    stage_A_mega<1>(Ax, esrc, hv, arow, q4);
    stage_B(0, Bt0);
    __syncthreads();

    f32x4v acc[2][4];
    #pragma unroll
    for (int mf = 0; mf < 2; ++mf)
      #pragma unroll
      for (int gg = 0; gg < 4; ++gg)
        acc[mf][gg] = (f32x4v){0.f, 0.f, 0.f, 0.f};

    #pragma unroll 1
    for (int j = 0; j < NTILE; ++j) {
      unsigned short* cur = (j & 1) ? Bt1 : Bt0;
      unsigned short* nxt = (j & 1) ? Bt0 : Bt1;
      if (j < NTILE - 1) stage_B(j + 1, nxt);
      const int jj  = (j < 18) ? j : (j < 30 ? j - 18 : j - 30);
      const int ks0 = (jj % 6) * 2;
      #pragma unroll
      for (int kh = 0; kh < 2; ++kh) {
        bf16x8v af0 = *(const bf16x8v*)&Ax[((ks0 + kh) * 4 + wm * 2) * 512 + lane * 8];
        bf16x8v af1 = *(const bf16x8v*)&Ax[((ks0 + kh) * 4 + wm * 2 + 1) * 512 + lane * 8];
        #pragma unroll
        for (int gg = 0; gg < 4; ++gg) {
          bf16x8v bfr = *(const bf16x8v*)&cur[(kh * 8 + wc * 4 + gg) * 512 + lane * 8];
          acc[0][gg] = __builtin_amdgcn_mfma_f32_16x16x32_bf16(af0, bfr, acc[0][gg], 0, 0, 0);
          acc[1][gg] = __builtin_amdgcn_mfma_f32_16x16x32_bf16(af1, bfr, acc[1][gg], 0, 0, 0);
        }
      }
      __syncthreads();
      if (j == 17)      { stage_A_mega<2>(Ax, esrc, hv, arow, q4); __syncthreads(); }
      else if (j == 29) { stage_A_mega<3>(Ax, esrc, hv, arow, q4); __syncthreads(); }
    }

    // epilogue: bias + cell update (c in regs), h -> L3 via agent atomics
    float* hcur = (g & 1) ? hB : hA;
    #pragma unroll
    for (int mf = 0; mf < 2; ++mf) {
      #pragma unroll
      for (int r = 0; r < 4; ++r) {
        float zi = acc[mf][0][r] + (enc ? ebs[0] : dbs[0]);
        float zf = acc[mf][1][r] + (enc ? ebs[1] : dbs[1]);
        float zg = acc[mf][2][r] + (enc ? ebs[2] : dbs[2]);
        float zo = acc[mf][3][r] + (enc ? ebs[3] : dbs[3]);
        int rr = (mf * 4 + r);
        float co = c_reg[mf][r];
        float cn = sigf(zf) * co + sigf(zi) * tanhf(zg);
        c_reg[mf][r] = cn;
        float hn = sigf(zo) * tanhf(cn);
        int row = m0 + wm * 32 + mf * 16 + l4 * 4 + r;
        (void)rr;
        __hip_atomic_store((unsigned int*)&hcur[(size_t)row * H_DIM + col],
                           __float_as_uint(hn), __ATOMIC_RELAXED, __HIP_MEMORY_SCOPE_AGENT);
      }
    }
    group_arrive(flag); ++E;

    // ================= declog epoch (decoder only) =================
    if (!enc) {
      const int t = g - S_LEN;
      group_wait(flag, 8 * E);

      const int r0d = m0 + nb * 8;
      const int wv  = tid >> 6;
      const int v0  = tid * 2;
      const float* hrd = (g & 1) ? hB : hA;

      #pragma unroll
      for (int s = 0; s < 2; ++s) {
        int f4 = s * 256 + tid;
        int row = f4 >> 6, q = f4 & 63;
        const unsigned long long* p =
            (const unsigned long long*)(hrd + (size_t)(r0d + row) * H_DIM + q * 4);
        unsigned long long u0 = __hip_atomic_load(p,     __ATOMIC_RELAXED, __HIP_MEMORY_SCOPE_AGENT);
        unsigned long long u1 = __hip_atomic_load(p + 1, __ATOMIC_RELAXED, __HIP_MEMORY_SCOPE_AGENT);
        dAs[row][q * 4 + 0] = __uint_as_float((unsigned)u0);
        dAs[row][q * 4 + 1] = __uint_as_float((unsigned)(u0 >> 32));
        dAs[row][q * 4 + 2] = __uint_as_float((unsigned)u1);
        dAs[row][q * 4 + 3] = __uint_as_float((unsigned)(u1 >> 32));
      }
      {
        #pragma unroll
        for (int s = 0; s < 2; ++s) {
          const float* src = fcW + (size_t)(v0 + s) * H_DIM;
          float4 w0 = *(const float4*)(src + 0);
          float4 w1 = *(const float4*)(src + 4);
          float4 w2 = *(const float4*)(src + 8);
          float4 w3 = *(const float4*)(src + 12);
          float wr0[16] = {w0.x, w0.y, w0.z, w0.w, w1.x, w1.y, w1.z, w1.w,
                           w2.x, w2.y, w2.z, w2.w, w3.x, w3.y, w3.z, w3.w};
          #pragma unroll
          for (int q = 0; q < 16; ++q) dBs[0][q][v0 + s] = wr0[q];
        }
      }
      __syncthreads();

      float dacc[2][8] = {};
      #pragma unroll 1
      for (int j = 0; j < 16; ++j) {
        const int buf = j & 1;
        float wr[2][16];
        if (j < 15) {
          #pragma unroll
          for (int s = 0; s < 2; ++s) {
            const float* src = fcW + (size_t)(v0 + s) * H_DIM + (j + 1) * 16;
            float4 w0 = *(const float4*)(src + 0);
            float4 w1 = *(const float4*)(src + 4);
            float4 w2 = *(const float4*)(src + 8);
            float4 w3 = *(const float4*)(src + 12);
            wr[s][0]=w0.x; wr[s][1]=w0.y; wr[s][2]=w0.z; wr[s][3]=w0.w;
            wr[s][4]=w1.x; wr[s][5]=w1.y; wr[s][6]=w1.z; wr[s][7]=w1.w;
            wr[s][8]=w2.x; wr[s][9]=w2.y; wr[s][10]=w2.z; wr[s][11]=w2.w;
            wr[s][12]=w3.x; wr[s][13]=w3.y; wr[s][14]=w3.z; wr[s][15]=w3.w;
          }
        }
        const int k0 = j * 16;
        #pragma unroll
        for (int kk = 0; kk < 16; ++kk) {
          float a0 = dAs[wv * 2 + 0][k0 + kk];
          float a1 = dAs[wv * 2 + 1][k0 + kk];
          #pragma unroll
          for (int i = 0; i < 8; ++i) {
            float bv = dBs[buf][kk][lane + 64 * i];
            dacc[0][i] = fmaf(a0, bv, dacc[0][i]);
            dacc[1][i] = fmaf(a1, bv, dacc[1][i]);
          }
        }
        if (j < 15) {
          #pragma unroll
          for (int s = 0; s < 2; ++s)
            #pragma unroll
            for (int q = 0; q < 16; ++q) dBs[buf ^ 1][q][v0 + s] = wr[s][q];
        }
        __syncthreads();
      }

      float bias[8];
      #pragma unroll
      for (int i = 0; i < 8; ++i) bias[i] = fcb[lane + 64 * i];

      #pragma unroll
      for (int r = 0; r < 2; ++r) {
        int row = r0d + wv * 2 + r;
        float* op = out + (size_t)row * T * V_DIM + (size_t)t * V_DIM;
        float best = -INFINITY;
        int   bi   = 0x7fffffff;
        #pragma unroll
        for (int i = 0; i < 8; ++i) {
          float x = dacc[r][i] + bias[i];
          op[lane + 64 * i] = x;
          if (x > best) { best = x; bi = lane + 64 * i; }
        }
        #pragma unroll
        for (int off = 32; off; off >>= 1) {
          float ov = __shfl_xor(best, off);
          int   oi = __shfl_xor(bi, off);
          if (ov > best || (ov == best && oi < bi)) { best = ov; bi = oi; }
        }
        if (lane == 0)
          __hip_atomic_store(&tok[row], bi, __ATOMIC_RELAXED, __HIP_MEMORY_SCOPE_AGENT);
      }
      group_arrive(flag); ++E;
    }
  }
}

extern "C" void kernel_launch(void* const* d_in, const int* in_sizes, int n_in,
                              void* d_out, int out_size, void* d_ws, size_t ws_size,
                              hipStream_t stream) {
  const int*   source  = (const int*)d_in[0];
  const float* enc_Wih = (const float*)d_in[3];
  const float* enc_Whh = (const float*)d_in[4];
  const float* enc_emb = (const float*)d_in[2];
  const float* enc_bih = (const float*)d_in[5];
  const float* enc_bhh = (const float*)d_in[6];
  const float* dec_emb = (const float*)d_in[7];
  const float* dec_Wih = (const float*)d_in[8];
  const float* dec_Whh = (const float*)d_in[9];
  const float* dec_bih = (const float*)d_in[10];
  const float* dec_bhh = (const float*)d_in[11];
  const float* fc_W    = (const float*)d_in[12];
  const float* fc_b    = (const float*)d_in[13];
  float* out = (float*)d_out;

  const int B = in_sizes[0] / S_LEN;              // 2048
  const int T = out_size / (B * V_DIM);           // 48

  const size_t BH = (size_t)B * H_DIM;
  const size_t WFSZ = (size_t)8 * NTILE * TILE_SHORTS;   // shorts per set
  float* hA  = (float*)d_ws;
  float* hB  = hA + BH;
  int*   tok = (int*)(hB + BH);
  unsigned short* We = (unsigned short*)(tok + B);
  unsigned short* Wd = We + WFSZ;
  int* flags = (int*)(Wd + WFSZ);

  prep_weights<<<dim3(577), dim3(256), 0, stream>>>(
      enc_Wih, enc_Whh, dec_Wih, dec_Whh, We, Wd, tok, flags);

  seq2seq_mega<<<dim3(256), dim3(256), 0, stream>>>(
      source,
      enc_emb, enc_bih, enc_bhh,
      dec_emb, dec_bih, dec_bhh,
      We, Wd, fc_W, fc_b,
      out, hA, hB, tok, flags, T);
}

// Round 11
// 3968.780 us; speedup vs baseline: 1.1959x; 1.1959x over previous
//
#include <hip/hip_runtime.h>
#include <cmath>

#define S_LEN 32
#define E_DIM 128
#define H_DIM 256
#define V_DIM 512
#define NTILE 36            // BK=64: pass1 18 (a1 x w1w2w3), pass2 12, pass3 6
#define TILE_SHORTS 8192    // 16 frags x 64 lanes x 8 shorts = 16 KB
#define A_SHORTS 24576      // 12 ksub x 4 rowblk x 64 lanes x 8 = 48 KB

typedef __attribute__((ext_vector_type(8))) short bf16x8v;
typedef __attribute__((ext_vector_type(4))) float f32x4v;

__device__ __forceinline__ float sigf(float x) { return 1.0f / (1.0f + expf(-x)); }

__device__ __forceinline__ unsigned short f2bf(float x) {      // RNE
  unsigned int b = __float_as_uint(x);
  b += 0x7FFFu + ((b >> 16) & 1u);
  return (unsigned short)(b >> 16);
}
__device__ __forceinline__ float bf2f(unsigned short u) {
  return __uint_as_float(((unsigned int)u) << 16);
}

template<int L>
__device__ __forceinline__ unsigned short lvl_bf(float x) {
  unsigned short b1 = f2bf(x);
  if (L == 1) return b1;
  float r1 = x - bf2f(b1);
  unsigned short b2 = f2bf(r1);
  if (L == 2) return b2;
  return f2bf(r1 - bf2f(b2));
}

__device__ __forceinline__ void gll16(const unsigned short* g, unsigned short* l) {
  __builtin_amdgcn_global_load_lds(
      (const __attribute__((address_space(1))) unsigned int*)g,
      (__attribute__((address_space(3))) unsigned int*)l, 16, 0, 0);
}

// ---------------------------------------------------------------------------
// prep: W fragment stream (BK=64 tiles) — EXACT round-9 layout + init tail.
// ---------------------------------------------------------------------------
__global__ void prep_weights(const float* __restrict__ eWih, const float* __restrict__ eWhh,
                             const float* __restrict__ dWih, const float* __restrict__ dWhh,
                             unsigned short* __restrict__ We, unsigned short* __restrict__ Wd,
                             float* __restrict__ h0, float* __restrict__ c,
                             int* __restrict__ tok)
{
  const int b = blockIdx.x;
  if (b >= 576) {                         // ---- init tail: 64 blocks
    const int pb = b - 576;
    const int gt = pb * 256 + threadIdx.x;     // 0..16383
    float4 z = make_float4(0.f, 0.f, 0.f, 0.f);
    float4* p0 = (float4*)h0;
    float4* pc = (float4*)c;
    for (int i = gt; i < 131072; i += 16384) { p0[i] = z; pc[i] = z; }
    if (gt < 2048) tok[gt] = 0;
    return;
  }
  const int j    = b % NTILE;
  const int rest = b / NTILE;
  const int nb   = rest & 7;
  const int set  = rest >> 3;
  const float* Wih = set ? dWih : eWih;
  const float* Whh = set ? dWhh : eWhh;
  unsigned short* dst = (set ? Wd : We) + ((size_t)nb * NTILE + j) * TILE_SHORTS;
  const int jj = (j < 18) ? j : (j < 30 ? j - 18 : j - 30);

  for (int cpos = threadIdx.x; cpos < 1024; cpos += 256) {
    int fi = cpos >> 6, l = cpos & 63;
    int kh = fi >> 3, wc = (fi >> 2) & 1, g = fi & 3;
    int n   = g * H_DIM + nb * 32 + wc * 16 + (l & 15);
    int sk0 = jj * 64 + kh * 32 + (l >> 4) * 8;
    int lvl = sk0 / 384;
    int kk  = sk0 - lvl * 384;
    unsigned short o8[8];
    #pragma unroll
    for (int e = 0; e < 8; ++e) {
      int k = kk + e;
      float v = (k < E_DIM) ? Wih[(size_t)n * E_DIM + k]
                            : Whh[(size_t)n * H_DIM + (k - E_DIM)];
      unsigned short b1 = f2bf(v);
      float r1 = v - bf2f(b1);
      unsigned short b2 = f2bf(r1);
      unsigned short b3 = f2bf(r1 - bf2f(b2));
      o8[e] = (lvl == 0) ? b1 : (lvl == 1) ? b2 : b3;
    }
    uint4 pk;
    pk.x = (unsigned)o8[0] | ((unsigned)o8[1] << 16);
    pk.y = (unsigned)o8[2] | ((unsigned)o8[3] << 16);
    pk.z = (unsigned)o8[4] | ((unsigned)o8[5] << 16);
    pk.w = (unsigned)o8[6] | ((unsigned)o8[7] << 16);
    *(uint4*)&dst[(size_t)cpos * 8] = pk;
  }
}

// stage level-L bf16 of A=[emb[idx]|h_in] into fragment layout — EXACT round-9
template<int L>
__device__ __forceinline__ void stage_A(unsigned short* Ax,
                                        const float* __restrict__ esrc,
                                        const float* __restrict__ hsrc,
                                        int arow, int q4) {
  const int rowblk = arow >> 4;
  const int rlo    = arow & 15;
  #pragma unroll
  for (int j = 0; j < 8; ++j) {
    int k0 = q4 * 4 + 16 * j;                 // 0..124
    float4 v = *(const float4*)(esrc + k0);
    unsigned short s0 = lvl_bf<L>(v.x), s1 = lvl_bf<L>(v.y),
                   s2 = lvl_bf<L>(v.z), s3 = lvl_bf<L>(v.w);
    uint2 p; p.x = (unsigned)s0 | ((unsigned)s1 << 16);
             p.y = (unsigned)s2 | ((unsigned)s3 << 16);
    int lane_w = rlo + ((k0 & 31) >> 3) * 16;
    *(uint2*)&Ax[(((k0 >> 5) * 4 + rowblk) * 64 + lane_w) * 8 + (k0 & 7)] = p;
  }
  #pragma unroll
  for (int j = 0; j < 16; ++j) {
    int k0 = q4 * 4 + 16 * j;                 // 0..252
    int kA = E_DIM + k0;
    float4 v = *(const float4*)(hsrc + k0);
    unsigned short s0 = lvl_bf<L>(v.x), s1 = lvl_bf<L>(v.y),
                   s2 = lvl_bf<L>(v.z), s3 = lvl_bf<L>(v.w);
    uint2 p; p.x = (unsigned)s0 | ((unsigned)s1 << 16);
             p.y = (unsigned)s2 | ((unsigned)s3 << 16);
    int lane_w = rlo + ((kA & 31) >> 3) * 16;
    *(uint2*)&Ax[(((kA >> 5) * 4 + rowblk) * 64 + lane_w) * 8 + (kA & 7)] = p;
  }
}

// ---------------------------------------------------------------------------
// LSTM step, bf16 triple-split 6-term MFMA — numerics IDENTICAL to rounds 7-10.
// NEW: 4-deep B-tile ring + counted vmcnt + RAW s_barrier (no implicit drain):
// loads for tiles j+1, j+2 stay in flight across each barrier (T3/T4).
// LDS = 48 KB A + 4 x 16 KB B = 112 KB (1 block/CU).
// ---------------------------------------------------------------------------
__launch_bounds__(256)
__global__ void lstm_mfma_kernel(const float* __restrict__ emb,
                                 const int* __restrict__ idx_src, int idx_stride, int idx_off,
                                 const unsigned short* __restrict__ Wf,
                                 const float* __restrict__ bih, const float* __restrict__ bhh,
                                 const float* __restrict__ h_in,
                                 float* __restrict__ h_out, float* __restrict__ c)
{
  __shared__ __align__(16) unsigned short smem[A_SHORTS + 4 * TILE_SHORTS]; // 112 KB
  unsigned short* Ax    = smem;
  unsigned short* Bbase = smem + A_SHORTS;

  const int tid  = threadIdx.x;
  const int lane = tid & 63;
  const int w    = tid >> 6;
  const int m0 = blockIdx.x * 64;
  const int nb = blockIdx.y;

  const int arow = tid >> 2;
  const int q4   = tid & 3;
  const int token = idx_src[(size_t)(m0 + arow) * idx_stride + idx_off];
  const float* esrc = emb + (size_t)token * E_DIM;
  const float* hsrc = h_in + (size_t)(m0 + arow) * H_DIM;

  const unsigned short* wstream = Wf + (size_t)nb * (NTILE * TILE_SHORTS);

  auto stage_B = [&](int j) {
    const unsigned short* src = wstream + (size_t)j * TILE_SHORTS + w * 2048 + lane * 8;
    unsigned short* dstp = Bbase + (size_t)(j & 3) * TILE_SHORTS + w * 2048;
    #pragma unroll
    for (int i = 0; i < 4; ++i) gll16(src + i * 512, dstp + i * 512);
  };

  stage_A<1>(Ax, esrc, hsrc, arow, q4);
  stage_B(0);
  stage_B(1);

  const int wm = (tid >> 6) & 1;
  const int wc = tid >> 7;

  f32x4v acc[2][4];
  #pragma unroll
  for (int mf = 0; mf < 2; ++mf)
    #pragma unroll
    for (int g = 0; g < 4; ++g)
      acc[mf][g] = (f32x4v){0.f, 0.f, 0.f, 0.f};

  #pragma unroll 1
  for (int j = 0; j < NTILE; ++j) {
    // A-level switch: extra barrier orders restage writes after MFMA(j-1) reads
    if (j == 18) { __builtin_amdgcn_s_barrier(); stage_A<2>(Ax, esrc, hsrc, arow, q4); }
    if (j == 30) { __builtin_amdgcn_s_barrier(); stage_A<3>(Ax, esrc, hsrc, arow, q4); }

    if (j < NTILE - 2) stage_B(j + 2);   // keep 2 tiles in flight

    if (j < NTILE - 2)       asm volatile("s_waitcnt vmcnt(8) lgkmcnt(0)" ::: "memory");
    else if (j == NTILE - 2) asm volatile("s_waitcnt vmcnt(4) lgkmcnt(0)" ::: "memory");
    else                     asm volatile("s_waitcnt vmcnt(0) lgkmcnt(0)" ::: "memory");
    __builtin_amdgcn_s_barrier();        // raw barrier: no vmcnt drain

    const unsigned short* cur = Bbase + (size_t)(j & 3) * TILE_SHORTS;
    const int jj  = (j < 18) ? j : (j < 30 ? j - 18 : j - 30);
    const int ks0 = (jj % 6) * 2;
    #pragma unroll
    for (int kh = 0; kh < 2; ++kh) {
      bf16x8v af0 = *(const bf16x8v*)&Ax[((ks0 + kh) * 4 + wm * 2) * 512 + lane * 8];
      bf16x8v af1 = *(const bf16x8v*)&Ax[((ks0 + kh) * 4 + wm * 2 + 1) * 512 + lane * 8];
      #pragma unroll
      for (int g = 0; g < 4; ++g) {
        bf16x8v bfr = *(const bf16x8v*)&cur[(kh * 8 + wc * 4 + g) * 512 + lane * 8];
        acc[0][g] = __builtin_amdgcn_mfma_f32_16x16x32_bf16(af0, bfr, acc[0][g], 0, 0, 0);
        acc[1][g] = __builtin_amdgcn_mfma_f32_16x16x32_bf16(af1, bfr, acc[1][g], 0, 0, 0);
      }
    }
  }

  // ---- epilogue: bias + cell update — EXACT rounds 7-10 version
  const int lr = tid & 15;
  const int l4 = lane >> 4;
  const int col = nb * 32 + wc * 16 + lr;
  float bs[4];
  #pragma unroll
  for (int g = 0; g < 4; ++g) bs[g] = bih[g * H_DIM + col] + bhh[g * H_DIM + col];

  #pragma unroll
  for (int mf = 0; mf < 2; ++mf) {
    #pragma unroll
    for (int r = 0; r < 4; ++r) {
      int row = m0 + wm * 32 + mf * 16 + l4 * 4 + r;
      float zi = acc[mf][0][r] + bs[0];
      float zf = acc[mf][1][r] + bs[1];
      float zg = acc[mf][2][r] + bs[2];
      float zo = acc[mf][3][r] + bs[3];
      float co = c[(size_t)row * H_DIM + col];
      float cn = sigf(zf) * co + sigf(zi) * tanhf(zg);
      c[(size_t)row * H_DIM + col] = cn;
      h_out[(size_t)row * H_DIM + col] = sigf(zo) * tanhf(cn);
    }
  }
}

// ---------------------------------------------------------------------------
// declog — EXACT round-9 version (known-good).
// ---------------------------------------------------------------------------
__launch_bounds__(256, 2)
__global__ void declog_kernel(const float* __restrict__ h,    // [B, H]
                              const float* __restrict__ fcW,  // [V, H]
                              const float* __restrict__ fcb,  // [V]
                              float* __restrict__ out,        // [B, T, V]
                              int* __restrict__ tok,          // [B]
                              int t, int T)
{
  __shared__ float As[8][264];
  __shared__ float Bs[2][16][V_DIM];

  const int tid  = threadIdx.x;
  const int lane = tid & 63;
  const int wv   = tid >> 6;
  const int r0   = blockIdx.x * 8;
  const int v0   = tid * 2;

  #pragma unroll
  for (int s = 0; s < 2; ++s) {
    int f4 = s * 256 + tid;
    int row = f4 >> 6, q = f4 & 63;
    float4 v = *(const float4*)(h + (size_t)(r0 + row) * H_DIM + q * 4);
    *(float4*)&As[row][q * 4] = v;
  }

  {
    #pragma unroll
    for (int s = 0; s < 2; ++s) {
      const float* src = fcW + (size_t)(v0 + s) * H_DIM;
      float4 w0 = *(const float4*)(src + 0);
      float4 w1 = *(const float4*)(src + 4);
      float4 w2 = *(const float4*)(src + 8);
      float4 w3 = *(const float4*)(src + 12);
      float wr[16] = {w0.x, w0.y, w0.z, w0.w, w1.x, w1.y, w1.z, w1.w,
                      w2.x, w2.y, w2.z, w2.w, w3.x, w3.y, w3.z, w3.w};
      #pragma unroll
      for (int q = 0; q < 16; ++q) Bs[0][q][v0 + s] = wr[q];
    }
  }
  __syncthreads();

  float acc[2][8] = {};

  #pragma unroll 1
  for (int j = 0; j < 16; ++j) {
    const int buf = j & 1;
    float wr[2][16];
    if (j < 15) {
      #pragma unroll
      for (int s = 0; s < 2; ++s) {
        const float* src = fcW + (size_t)(v0 + s) * H_DIM + (j + 1) * 16;
        float4 w0 = *(const float4*)(src + 0);
        float4 w1 = *(const float4*)(src + 4);
        float4 w2 = *(const float4*)(src + 8);
        float4 w3 = *(const float4*)(src + 12);
        wr[s][0]=w0.x; wr[s][1]=w0.y; wr[s][2]=w0.z; wr[s][3]=w0.w;
        wr[s][4]=w1.x; wr[s][5]=w1.y; wr[s][6]=w1.z; wr[s][7]=w1.w;
        wr[s][8]=w2.x; wr[s][9]=w2.y; wr[s][10]=w2.z; wr[s][11]=w2.w;
        wr[s][12]=w3.x; wr[s][13]=w3.y; wr[s][14]=w3.z; wr[s][15]=w3.w;
      }
    }
    const int k0 = j * 16;
    #pragma unroll
    for (int kk = 0; kk < 16; ++kk) {
      float a0 = As[wv * 2 + 0][k0 + kk];
      float a1 = As[wv * 2 + 1][k0 + kk];
      #pragma unroll
      for (int i = 0; i < 8; ++i) {
        float b = Bs[buf][kk][lane + 64 * i];
        acc[0][i] = fmaf(a0, b, acc[0][i]);
        acc[1][i] = fmaf(a1, b, acc[1][i]);
      }
    }
    if (j < 15) {
      #pragma unroll
      for (int s = 0; s < 2; ++s)
        #pragma unroll
        for (int q = 0; q < 16; ++q) Bs[buf ^ 1][q][v0 + s] = wr[s][q];
    }
    __syncthreads();
  }

  float bias[8];
  #pragma unroll
  for (int i = 0; i < 8; ++i) bias[i] = fcb[lane + 64 * i];

  #pragma unroll
  for (int r = 0; r < 2; ++r) {
    int row = r0 + wv * 2 + r;
    float* op = out + (size_t)row * T * V_DIM + (size_t)t * V_DIM;
    float best = -INFINITY;
    int   bi   = 0x7fffffff;
    #pragma unroll
    for (int i = 0; i < 8; ++i) {
      float x = acc[r][i] + bias[i];
      op[lane + 64 * i] = x;
      if (x > best) { best = x; bi = lane + 64 * i; }
    }
    #pragma unroll
    for (int off = 32; off; off >>= 1) {
      float ov = __shfl_xor(best, off);
      int   oi = __shfl_xor(bi, off);
      if (ov > best || (ov == best && oi < bi)) { best = ov; bi = oi; }
    }
    if (lane == 0) tok[row] = bi;
  }
}

extern "C" void kernel_launch(void* const* d_in, const int* in_sizes, int n_in,
                              void* d_out, int out_size, void* d_ws, size_t ws_size,
                              hipStream_t stream) {
  const int*   source  = (const int*)d_in[0];
  const float* enc_emb = (const float*)d_in[2];
  const float* enc_Wih = (const float*)d_in[3];
  const float* enc_Whh = (const float*)d_in[4];
  const float* enc_bih = (const float*)d_in[5];
  const float* enc_bhh = (const float*)d_in[6];
  const float* dec_emb = (const float*)d_in[7];
  const float* dec_Wih = (const float*)d_in[8];
  const float* dec_Whh = (const float*)d_in[9];
  const float* dec_bih = (const float*)d_in[10];
  const float* dec_bhh = (const float*)d_in[11];
  const float* fc_W    = (const float*)d_in[12];
  const float* fc_b    = (const float*)d_in[13];
  float* out = (float*)d_out;

  const int B = in_sizes[0] / S_LEN;              // 2048
  const int T = out_size / (B * V_DIM);           // 48

  const size_t BH = (size_t)B * H_DIM;
  const size_t WFSZ = (size_t)8 * NTILE * TILE_SHORTS;   // shorts per set
  float* h0  = (float*)d_ws;
  float* h1  = h0 + BH;
  float* c   = h1 + BH;
  int*   tok = (int*)(c + BH);
  unsigned short* We = (unsigned short*)(tok + B);
  unsigned short* Wd = We + WFSZ;

  prep_weights<<<dim3(576 + 64), dim3(256), 0, stream>>>(
      enc_Wih, enc_Whh, dec_Wih, dec_Whh, We, Wd, h0, c, tok);

  dim3 blk(256);
  dim3 g_lstm(B / 64, H_DIM / 32);    // (32, 8) = 256 blocks
  dim3 g_declog(B / 8);               // 256 blocks

  const float* hin = h0;
  float* hout = h1;

  // ---- encoder ----
  for (int s = 0; s < S_LEN; ++s) {
    lstm_mfma_kernel<<<g_lstm, blk, 0, stream>>>(
        enc_emb, source, S_LEN, s, We, enc_bih, enc_bhh, hin, hout, c);
    const float* tmp = hout; hout = (float*)hin; hin = tmp;
  }

  // ---- decoder (greedy, autoregressive) ----
  for (int t = 0; t < T; ++t) {
    lstm_mfma_kernel<<<g_lstm, blk, 0, stream>>>(
        dec_emb, tok, 1, 0, Wd, dec_bih, dec_bhh, hin, hout, c);
    const float* tmp = hout; hout = (float*)hin; hin = tmp;
    declog_kernel<<<g_declog, blk, 0, stream>>>(hin, fc_W, fc_b, out, tok, t, T);
  }
}